// Round 9
// baseline (794.580 us; speedup 1.0000x reference)
//
#include <hip/hip_runtime.h>
#include <hip/hip_bf16.h>

typedef unsigned short u16;
typedef short short8 __attribute__((ext_vector_type(8)));
typedef float f32x4 __attribute__((ext_vector_type(4)));

#define B_    32
#define N_    512
#define INF   1024
#define OUTF  4096
#define ROWS  16384     // B_*N_
#define HID_  128
#define CTRL  3072

__device__ __forceinline__ u16 f2bf(float f) {
    union { float fv; unsigned int u; } v; v.fv = f;
    unsigned int x = v.u;
    unsigned int r = (x + 0x7fffu + ((x >> 16) & 1u)) >> 16;
    return (u16)r;
}

// async global->LDS, 16B per lane. lds ptr must be the WAVE-UNIFORM base;
// lane l deposits at base + l*16.
__device__ __forceinline__ void gll16(const void* g, const void* l) {
    __builtin_amdgcn_global_load_lds(
        (__attribute__((address_space(1))) void*)(unsigned long long)g,
        (__attribute__((address_space(3))) void*)(unsigned int)(unsigned long long)l,
        16, 0, 0);
}

// by-VALUE 16-way select (cndmask chain; no address taken -> no scratch demotion)
__device__ __forceinline__ float sel16(float4 a, float4 b, float4 c4, float4 d, int m) {
    float v = a.x;
    v = (m == 1) ? a.y : v;  v = (m == 2) ? a.z : v;  v = (m == 3) ? a.w : v;
    v = (m == 4) ? b.x : v;  v = (m == 5) ? b.y : v;  v = (m == 6) ? b.z : v;  v = (m == 7) ? b.w : v;
    v = (m == 8) ? c4.x : v; v = (m == 9) ? c4.y : v; v = (m == 10) ? c4.z : v; v = (m == 11) ? c4.w : v;
    v = (m == 12) ? d.x : v; v = (m == 13) ? d.y : v; v = (m == 14) ? d.z : v; v = (m == 15) ? d.w : v;
    return v;
}

// ---------------- stats (partial sums) + x->bf16 convert -------------------
__global__ __launch_bounds__(256) void k_stats(const float* __restrict__ x,
        u16* __restrict__ xb, float* __restrict__ ps, float* __restrict__ pq) {
    int b = blockIdx.y, bn = blockIdx.x, t = threadIdx.x;
    const float4* xp = (const float4*)(x + (size_t)b*(N_*INF) + (size_t)bn*64*INF);
    size_t obase = ((size_t)b*(N_*INF) + (size_t)bn*64*INF) >> 2;
    float sx=0, sy=0, sz=0, sw=0, qx=0, qy=0, qz=0, qw=0;
    for (int n = 0; n < 64; ++n) {
        float4 v = xp[n*256 + t];
        sx += v.x; sy += v.y; sz += v.z; sw += v.w;
        qx += v.x*v.x; qy += v.y*v.y; qz += v.z*v.z; qw += v.w*v.w;
        ushort4 o; o.x = f2bf(v.x); o.y = f2bf(v.y); o.z = f2bf(v.z); o.w = f2bf(v.w);
        ((ushort4*)xb)[obase + n*256 + t] = o;
    }
    int base = (b*8 + bn)*256 + t;
    float4 s4; s4.x=sx; s4.y=sy; s4.z=sz; s4.w=sw;
    float4 q4; q4.x=qx; q4.y=qy; q4.z=qz; q4.w=qw;
    ((float4*)ps)[base] = s4;
    ((float4*)pq)[base] = q4;
}

// ---------------- control MLP: coalesced wave-per-row GEMV -----------------
__global__ __launch_bounds__(256) void k_ctrl(const float* __restrict__ x,
    const float* __restrict__ ps, const float* __restrict__ pq,
    const float* __restrict__ w1, const float* __restrict__ b1,
    const float* __restrict__ rcw, const float* __restrict__ rcb,
    const float* __restrict__ rgw, const float* __restrict__ rgb,
    const float* __restrict__ scw, const float* __restrict__ scb,
    const float* __restrict__ sgw, const float* __restrict__ sgb,
    float* __restrict__ rc, float* __restrict__ rg,
    float* __restrict__ sc, float* __restrict__ sg)
{
    __shared__ float zs[CTRL];
    __shared__ float hs[HID_];
    int b = blockIdx.x, t = threadIdx.x;
    for (int d = t; d < 1024; d += 256) {
        float ssum = 0.f, qsum = 0.f;
        for (int j = 0; j < 8; ++j) {
            ssum += ps[(b*8 + j)*1024 + d];
            qsum += pq[(b*8 + j)*1024 + d];
        }
        float mean = ssum * (1.0f/512.0f);
        float var  = qsum * (1.0f/512.0f) - mean*mean;
        zs[d]        = x[(size_t)b*(N_*INF) + d];
        zs[1024 + d] = mean;
        zs[2048 + d] = var;
    }
    __syncthreads();
    int w = t >> 6, l = t & 63;
    const float4* zp = (const float4*)zs;
    for (int i = w; i < HID_; i += 4) {
        const float4* wr = (const float4*)(w1 + (size_t)i*CTRL);
        float acc = 0.f;
        #pragma unroll
        for (int c = 0; c < 12; ++c) {
            float4 a4 = wr[l + 64*c];
            float4 z4 = zp[l + 64*c];
            acc += a4.x*z4.x + a4.y*z4.y + a4.z*z4.z + a4.w*z4.w;
        }
        #pragma unroll
        for (int o2 = 32; o2 > 0; o2 >>= 1) acc += __shfl_down(acc, o2, 64);
        if (l == 0) {
            float u = acc + b1[i];
            hs[i] = 0.5f*u*(1.0f + tanhf(0.7978845608028654f*(u + 0.044715f*u*u*u)));
        }
    }
    __syncthreads();
    if (t < 8) {
        float a = rcb[t]; const float* wv = rcw + t*HID_;
        for (int i = 0; i < HID_; ++i) a += hs[i]*wv[i];
        rc[b*8 + t] = a;
    } else if (t < 16) {
        int j = t - 8;
        float a = scb[j]; const float* wv = scw + j*HID_;
        for (int i = 0; i < HID_; ++i) a += hs[i]*wv[i];
        sc[b*8 + j] = a;
    } else if (t == 16) {
        float a = rgb[0] - 4.0f;
        for (int i = 0; i < HID_; ++i) a += hs[i]*rgw[i];
        rg[b] = 1.0f/(1.0f + expf(-a));
    } else if (t == 17) {
        float a = sgb[0] - 2.5f;
        for (int i = 0; i < HID_; ++i) a += hs[i]*sgw[i];
        sg[b] = 1.0f/(1.0f + expf(-a));
    }
}

// ---------------- basis norms from Gram blocks of G ------------------------
__global__ __launch_bounds__(64) void k_norms(const float* __restrict__ G,
        float* __restrict__ norms) {
    int k = blockIdx.x, t = threadIdx.x;
    int i = t >> 3, j = t & 7;
    float A  = G[(16*k + i)*128     + 16*k + j];
    float C  = G[(16*k + 8 + i)*128 + 16*k + 8 + j];
    float D  = G[(16*k + 8 + i)*128 + 16*k + j];
    float Dj = G[(16*k + 8 + j)*128 + 16*k + i];
    float term = A*C - D*Dj;
    #pragma unroll
    for (int o2 = 32; o2 > 0; o2 >>= 1) term += __shfl_down(term, o2, 64);
    if (t == 0) norms[k] = fmaxf(sqrtf(fmaxf(2.0f*term, 0.0f)), 1e-6f);
}

// ---------------- build U (1024x128 f32) and U^T (bf16, 128x1024) ----------
__global__ __launch_bounds__(256) void k_buildU(const float* __restrict__ L,
        const float* __restrict__ R, float* __restrict__ U, u16* __restrict__ Utb) {
    int idx = blockIdx.x*256 + threadIdx.x;
    int d = idx >> 7, col = idx & 127;
    int k = col >> 4, rr = col & 15;
    float v = (rr < 8) ? L[((size_t)k<<13) + (d<<3) + rr]
                       : R[((size_t)k<<13) + (d<<3) + (rr-8)];
    U[idx] = v;
    Utb[col*1024 + d] = f2bf(v);
}

// ---------------- G = U^T U (128x128) --------------------------------------
__global__ __launch_bounds__(256) void k_gram(const float* __restrict__ U,
        float* __restrict__ G) {
    int e = blockIdx.x*256 + threadIdx.x;
    int i = e >> 7, j = e & 127;
    float a = 0.f;
    for (int d = 0; d < 1024; ++d) a += U[d*128 + i]*U[d*128 + j];
    G[e] = a;
}

// ---------------- per-batch 128x128 inversion, register-resident GJ --------
__global__ __launch_bounds__(1024, 4) void k_solve(const float* __restrict__ G,
    const float* __restrict__ rc, const float* __restrict__ norms,
    const float* __restrict__ rg, u16* __restrict__ Ptb)
{
    __shared__ float smem[16384];          // 64KB; first 512 floats = pivot bufs
    float* prow = smem;                    // [2][128]
    float* pcol = smem + 256;              // [2][128]
    int b = blockIdx.x, t = threadIdx.x;
    int r = t & 127, s = t >> 7;           // s is wave-uniform
    int kr = r >> 4, rr = r & 15;
    float a_r = rc[b*8 + kr] / norms[kr];
    int partner = (rr < 8) ? (kr*16 + 8 + rr) : (kr*16 + rr - 8);
    float sg0 = (rr < 8) ? -0.5f*a_r : 0.5f*a_r;
    float4 o0, o1, o2, o3;
    {
        const float4* Gp = (const float4*)(G + (size_t)partner*128 + 16*s);
        float4 g0 = Gp[0], g1 = Gp[1], g2 = Gp[2], g3 = Gp[3];
        int base = 16*s;
        o0.x = sg0*g0.x + ((r == base+0 ) ? 1.f : 0.f);
        o0.y = sg0*g0.y + ((r == base+1 ) ? 1.f : 0.f);
        o0.z = sg0*g0.z + ((r == base+2 ) ? 1.f : 0.f);
        o0.w = sg0*g0.w + ((r == base+3 ) ? 1.f : 0.f);
        o1.x = sg0*g1.x + ((r == base+4 ) ? 1.f : 0.f);
        o1.y = sg0*g1.y + ((r == base+5 ) ? 1.f : 0.f);
        o1.z = sg0*g1.z + ((r == base+6 ) ? 1.f : 0.f);
        o1.w = sg0*g1.w + ((r == base+7 ) ? 1.f : 0.f);
        o2.x = sg0*g2.x + ((r == base+8 ) ? 1.f : 0.f);
        o2.y = sg0*g2.y + ((r == base+9 ) ? 1.f : 0.f);
        o2.z = sg0*g2.z + ((r == base+10) ? 1.f : 0.f);
        o2.w = sg0*g2.w + ((r == base+11) ? 1.f : 0.f);
        o3.x = sg0*g3.x + ((r == base+12) ? 1.f : 0.f);
        o3.y = sg0*g3.y + ((r == base+13) ? 1.f : 0.f);
        o3.z = sg0*g3.z + ((r == base+14) ? 1.f : 0.f);
        o3.w = sg0*g3.w + ((r == base+15) ? 1.f : 0.f);
    }
    if (r == 0) {
        float4 v0 = o0, v1 = o1, v2 = o2, v3 = o3;
        if (s == 0) v0.x += 1.0f;
        *(float4*)(prow + 16*s +  0) = v0;
        *(float4*)(prow + 16*s +  4) = v1;
        *(float4*)(prow + 16*s +  8) = v2;
        *(float4*)(prow + 16*s + 12) = v3;
    }
    if (s == 0) pcol[r] = o0.x;
    __syncthreads();
    for (int c = 0; c < 128; ++c) {
        int buf = c & 1, nb = buf ^ 1;
        float fr = pcol[buf*128 + r];
        const float4* prp = (const float4*)(prow + buf*128 + 16*s);
        float4 p0 = prp[0], p1 = prp[1], p2 = prp[2], p3 = prp[3];
        float pv = prow[buf*128 + c] - 1.0f;   // un-marked pivot value
        float invp = 1.0f / pv;
        if (r == c) {
            int base = 16*s;
            o0.x = (base+0  == c) ? invp : o0.x*invp;
            o0.y = (base+1  == c) ? invp : o0.y*invp;
            o0.z = (base+2  == c) ? invp : o0.z*invp;
            o0.w = (base+3  == c) ? invp : o0.w*invp;
            o1.x = (base+4  == c) ? invp : o1.x*invp;
            o1.y = (base+5  == c) ? invp : o1.y*invp;
            o1.z = (base+6  == c) ? invp : o1.z*invp;
            o1.w = (base+7  == c) ? invp : o1.w*invp;
            o2.x = (base+8  == c) ? invp : o2.x*invp;
            o2.y = (base+9  == c) ? invp : o2.y*invp;
            o2.z = (base+10 == c) ? invp : o2.z*invp;
            o2.w = (base+11 == c) ? invp : o2.w*invp;
            o3.x = (base+12 == c) ? invp : o3.x*invp;
            o3.y = (base+13 == c) ? invp : o3.y*invp;
            o3.z = (base+14 == c) ? invp : o3.z*invp;
            o3.w = (base+15 == c) ? invp : o3.w*invp;
        } else {
            float fi = fr * invp;
            o0.x -= fi*p0.x; o0.y -= fi*p0.y; o0.z -= fi*p0.z; o0.w -= fi*p0.w;
            o1.x -= fi*p1.x; o1.y -= fi*p1.y; o1.z -= fi*p1.z; o1.w -= fi*p1.w;
            o2.x -= fi*p2.x; o2.y -= fi*p2.y; o2.z -= fi*p2.z; o2.w -= fi*p2.w;
            o3.x -= fi*p3.x; o3.y -= fi*p3.y; o3.z -= fi*p3.z; o3.w -= fi*p3.w;
        }
        int cn = c + 1;
        if (cn < 128) {
            if (r == cn) {
                float4 v0 = o0, v1 = o1, v2 = o2, v3 = o3;
                int base = 16*s;
                v0.x += (base+0  == cn) ? 1.f : 0.f;
                v0.y += (base+1  == cn) ? 1.f : 0.f;
                v0.z += (base+2  == cn) ? 1.f : 0.f;
                v0.w += (base+3  == cn) ? 1.f : 0.f;
                v1.x += (base+4  == cn) ? 1.f : 0.f;
                v1.y += (base+5  == cn) ? 1.f : 0.f;
                v1.z += (base+6  == cn) ? 1.f : 0.f;
                v1.w += (base+7  == cn) ? 1.f : 0.f;
                v2.x += (base+8  == cn) ? 1.f : 0.f;
                v2.y += (base+9  == cn) ? 1.f : 0.f;
                v2.z += (base+10 == cn) ? 1.f : 0.f;
                v2.w += (base+11 == cn) ? 1.f : 0.f;
                v3.x += (base+12 == cn) ? 1.f : 0.f;
                v3.y += (base+13 == cn) ? 1.f : 0.f;
                v3.z += (base+14 == cn) ? 1.f : 0.f;
                v3.w += (base+15 == cn) ? 1.f : 0.f;
                *(float4*)(prow + nb*128 + 16*s +  0) = v0;
                *(float4*)(prow + nb*128 + 16*s +  4) = v1;
                *(float4*)(prow + nb*128 + 16*s +  8) = v2;
                *(float4*)(prow + nb*128 + 16*s + 12) = v3;
            }
            if (s == (cn >> 4)) pcol[nb*128 + r] = sel16(o0, o1, o2, o3, cn & 15);
        }
        __syncthreads();
    }
    float as_ = rc[b*8 + s] / norms[s];
    float gg = rg[b];
    float na = -gg * as_, pa = gg * as_;
    smem[(16*s +  0)*128 + r] = na*o2.x;
    smem[(16*s +  1)*128 + r] = na*o2.y;
    smem[(16*s +  2)*128 + r] = na*o2.z;
    smem[(16*s +  3)*128 + r] = na*o2.w;
    smem[(16*s +  4)*128 + r] = na*o3.x;
    smem[(16*s +  5)*128 + r] = na*o3.y;
    smem[(16*s +  6)*128 + r] = na*o3.z;
    smem[(16*s +  7)*128 + r] = na*o3.w;
    smem[(16*s +  8)*128 + r] = pa*o0.x;
    smem[(16*s +  9)*128 + r] = pa*o0.y;
    smem[(16*s + 10)*128 + r] = pa*o0.z;
    smem[(16*s + 11)*128 + r] = pa*o0.w;
    smem[(16*s + 12)*128 + r] = pa*o1.x;
    smem[(16*s + 13)*128 + r] = pa*o1.y;
    smem[(16*s + 14)*128 + r] = pa*o1.z;
    smem[(16*s + 15)*128 + r] = pa*o1.w;
    __syncthreads();
    int r2 = t >> 3, s2 = t & 7;
    const float4* rp = (const float4*)(smem + r2*128 + 16*s2);
    float4 v0 = rp[0], v1 = rp[1], v2 = rp[2], v3 = rp[3];
    uint4 w0, w1;
    w0.x = f2bf(v0.x) | ((unsigned)f2bf(v0.y) << 16);
    w0.y = f2bf(v0.z) | ((unsigned)f2bf(v0.w) << 16);
    w0.z = f2bf(v1.x) | ((unsigned)f2bf(v1.y) << 16);
    w0.w = f2bf(v1.z) | ((unsigned)f2bf(v1.w) << 16);
    w1.x = f2bf(v2.x) | ((unsigned)f2bf(v2.y) << 16);
    w1.y = f2bf(v2.z) | ((unsigned)f2bf(v2.w) << 16);
    w1.z = f2bf(v3.x) | ((unsigned)f2bf(v3.y) << 16);
    w1.w = f2bf(v3.z) | ((unsigned)f2bf(v3.w) << 16);
    uint4* dst = (uint4*)(Ptb + ((size_t)(b*128 + r2))*128 + 16*s2);
    dst[0] = w0; dst[1] = w1;
}

// ---------------- output scale: 1 + sg*tanh(sc @ scale_basis) --------------
__global__ __launch_bounds__(256) void k_scale(const float* __restrict__ sc,
    const float* __restrict__ sbasis, const float* __restrict__ sg,
    float* __restrict__ scl) {
    int idx = blockIdx.x*256 + threadIdx.x;
    int b = idx >> 12, o = idx & 4095;
    float a = 0.f;
    #pragma unroll
    for (int k = 0; k < 8; ++k) a += sc[b*8 + k]*sbasis[(k<<12) + o];
    scl[idx] = 1.0f + sg[b]*tanhf(a);
}

// ---------------- f32 -> bf16 bulk convert ---------------------------------
__global__ __launch_bounds__(256) void k_cvt(const float* __restrict__ in,
        u16* __restrict__ out, int n4) {
    int i = blockIdx.x*256 + threadIdx.x;
    if (i < n4) {
        float4 v = ((const float4*)in)[i];
        ushort4 o; o.x=f2bf(v.x); o.y=f2bf(v.y); o.z=f2bf(v.z); o.w=f2bf(v.w);
        ((ushort4*)out)[i] = o;
    }
}

// ---------------- generic bf16 MFMA GEMM: C[m,n] = sum_k A[m,k]*Bt[n,k] ----
__global__ __launch_bounds__(256) void k_gemm_bt(const u16* __restrict__ A,
    const u16* __restrict__ Bt, u16* __restrict__ C,
    int M, int N, int K, long sA_, long sB_, long sC_)
{
    A  += (size_t)blockIdx.z * sA_;
    Bt += (size_t)blockIdx.z * sB_;
    C  += (size_t)blockIdx.z * sC_;
    int bm = blockIdx.y, bn = blockIdx.x;
    __shared__ __align__(16) u16 sA[128*64];
    __shared__ __align__(16) u16 sB[128*64];
    int tid = threadIdx.x;
    int wave = tid >> 6, lane = tid & 63;
    int wbase = tid & ~63;
    int wm = wave >> 1, wn = wave & 1;
    int quad = lane >> 4, l16 = lane & 15;
    f32x4 acc[4][4];
    #pragma unroll
    for (int i = 0; i < 4; ++i)
        #pragma unroll
        for (int j = 0; j < 4; ++j) { f32x4 z4 = {0.f,0.f,0.f,0.f}; acc[i][j] = z4; }
    int nk = K >> 6;
    for (int kt = 0; kt < nk; ++kt) {
        __syncthreads();
        #pragma unroll
        for (int q2 = 0; q2 < 4; ++q2) {
            int c = q2*256 + tid, row = c >> 3, kc = c & 7;
            gll16(A  + (size_t)(bm*128 + row)*K + kt*64 + kc*8, sA + (size_t)(q2*256 + wbase)*8);
            gll16(Bt + (size_t)(bn*128 + row)*K + kt*64 + kc*8, sB + (size_t)(q2*256 + wbase)*8);
        }
        __syncthreads();
        #pragma unroll
        for (int ks = 0; ks < 2; ++ks) {
            short8 af[4], bfv[4];
            #pragma unroll
            for (int i = 0; i < 4; ++i)
                af[i] = *(const short8*)(sA + (wm*64 + i*16 + l16)*64 + ks*32 + quad*8);
            #pragma unroll
            for (int j = 0; j < 4; ++j)
                bfv[j] = *(const short8*)(sB + (wn*64 + j*16 + l16)*64 + ks*32 + quad*8);
            #pragma unroll
            for (int i = 0; i < 4; ++i)
                #pragma unroll
                for (int j = 0; j < 4; ++j)
                    acc[i][j] = __builtin_amdgcn_mfma_f32_16x16x32_bf16(af[i], bfv[j], acc[i][j], 0, 0, 0);
        }
    }
    #pragma unroll
    for (int i = 0; i < 4; ++i)
        #pragma unroll
        for (int j = 0; j < 4; ++j) {
            int gcol = bn*128 + wn*64 + j*16 + l16;
            #pragma unroll
            for (int r = 0; r < 4; ++r) {
                int grow = bm*128 + wm*64 + i*16 + quad*4 + r;
                C[(size_t)grow*N + gcol] = f2bf(acc[i][j][r]);
            }
        }
}

// ---------------- main fused GEMM, 256x256 tile / 8 waves / BK=64 ----------
// out = (x W^T + Q V^T + bias) * scale.
// R7 verified base (177.5us, MfmaUtil 37%, bank-conflict 0) + THIS ROUND:
// 4-phase-per-tile interleave (T3+T5 per the 8-phase template, m196/m218/m233):
//   each phase = { per-phase ds_reads (12 at P0, 4 at P1-3) || 2-load stage of
//   next tile's segment } -> s_barrier -> lgkmcnt(0) -> setprio(1) -> 16 MFMA
//   -> setprio(0) -> s_barrier.  vmcnt(0) once per tile before P3's final
//   barrier (conservative drain: stages target only the non-read buffer;
//   all reads of a buffer complete (lgkmcnt0 + barrier) before it is staged).
// LDS swizzle unchanged: byte ^= ((byte>>7)&7)<<4 on pre-swizzled global src
// (linear gll16 dest) and on ds_read addrs -> conflict-free (measured 0).
__global__ __launch_bounds__(512, 2) void k_main(const u16* __restrict__ xb,
    const u16* __restrict__ Wb, const u16* __restrict__ Qb,
    const u16* __restrict__ Vb, const float* __restrict__ bias,
    const float* __restrict__ scale, float* __restrict__ out)
{
    __shared__ __align__(16) u16 lds[65536];       // 128 KB
    int flat = blockIdx.y * 16 + blockIdx.x;       // 0..1023
    int wg   = (flat & 7) * 128 + (flat >> 3);     // bijective XCD chunking
    int bm = wg >> 4, bn = wg & 15;                // 64 x 16
    int tid = threadIdx.x;
    int wave = tid >> 6, lane = tid & 63;
    int wm = wave >> 2, wn = wave & 3;             // 2 x 4 wave grid
    int quad = lane >> 4, l16 = lane & 15;

    // ---- staging constants (per thread) ----
    // dest (linear): seg_byte = wave*2048 + i*1024 + lane*16
    // logical = dest ^ ((dest>>7 & 7)<<4)  ->  row/col below
    int srow = wave*16 + (lane >> 3);                       // +8 for i=1
    int scol = (((lane & 7) ^ ((lane >> 3) & 7)) << 3);     // element col (x8)
    int arow0 = bm*256 + srow;
    int brow0 = bn*256 + srow;

    // ---- ds_read constants (byte offsets, swizzled) ----
    int cswz0 = (quad*16)      ^ ((l16 & 7) << 4);          // ks=0
    int cswz1 = (64 + quad*16) ^ ((l16 & 7) << 4);          // ks=1
    int abase = wm*16384 + l16*128;                         // A seg = wm
    int bbase = 32768 + (wn >> 1)*16384 + (wn & 1)*8192 + l16*128;

    // stage one segment (2 gll16) of tile kt into buf kt&1.
    // p=0: A rows 0-127 (A0), p=1: A rows 128-255 (A1),
    // p=2: B rows 0-127 (B0), p=3: B rows 128-255 (B1).
    auto stage2 = [&](int kt, int p) {
        u16* lb = lds + (kt & 1)*32768 + p*8192;
        const u16* S; int str, ko;
        if (kt < 16) { S = (p < 2) ? xb : Wb; str = 1024; ko = kt*64 + scol; }
        else         { S = (p < 2) ? Qb : Vb; str = 128;  ko = (kt-16)*64 + scol; }
        int r0 = ((p < 2) ? arow0 : brow0) + (p & 1)*128;
        gll16(S + (size_t)(r0    )*str + ko, lb + wave*1024);
        gll16(S + (size_t)(r0 + 8)*str + ko, lb + wave*1024 + 512);
    };

    f32x4 acc[8][4];
    #pragma unroll
    for (int m = 0; m < 8; ++m)
        #pragma unroll
        for (int n = 0; n < 4; ++n) { f32x4 z4 = {0.f,0.f,0.f,0.f}; acc[m][n] = z4; }

    // prologue: tile 0 fully staged into buf0
    #pragma unroll
    for (int p = 0; p < 4; ++p) stage2(0, p);
    asm volatile("s_waitcnt vmcnt(0)" ::: "memory");
    __builtin_amdgcn_s_barrier();
    __builtin_amdgcn_sched_barrier(0);

    for (int t = 0; t < 18; ++t) {
        const char* lb = (const char*)lds + (t & 1)*65536;
        short8 bfr[4][2];
        #pragma unroll
        for (int p = 0; p < 4; ++p) {
            // per-phase ds_reads (issued before the barrier; latency hides
            // under barrier wait + lgkmcnt)
            if (p == 0) {
                #pragma unroll
                for (int n = 0; n < 4; ++n) {
                    bfr[n][0] = *(const short8*)(lb + bbase + cswz0 + n*2048);
                    bfr[n][1] = *(const short8*)(lb + bbase + cswz1 + n*2048);
                }
            }
            short8 a0 = *(const short8*)(lb + abase + cswz0 + (2*p    )*2048);
            short8 a1 = *(const short8*)(lb + abase + cswz1 + (2*p    )*2048);
            short8 a2 = *(const short8*)(lb + abase + cswz0 + (2*p + 1)*2048);
            short8 a3 = *(const short8*)(lb + abase + cswz1 + (2*p + 1)*2048);
            // stage segment p of next tile into the opposite buffer
            if (t < 17) stage2(t + 1, p);
            __builtin_amdgcn_s_barrier();
            asm volatile("s_waitcnt lgkmcnt(0)" ::: "memory");
            __builtin_amdgcn_sched_barrier(0);
            __builtin_amdgcn_s_setprio(1);
            int m0 = 2*p, m1 = 2*p + 1;
            #pragma unroll
            for (int n = 0; n < 4; ++n) {
                acc[m0][n] = __builtin_amdgcn_mfma_f32_16x16x32_bf16(a0, bfr[n][0], acc[m0][n], 0, 0, 0);
                acc[m0][n] = __builtin_amdgcn_mfma_f32_16x16x32_bf16(a1, bfr[n][1], acc[m0][n], 0, 0, 0);
                acc[m1][n] = __builtin_amdgcn_mfma_f32_16x16x32_bf16(a2, bfr[n][0], acc[m1][n], 0, 0, 0);
                acc[m1][n] = __builtin_amdgcn_mfma_f32_16x16x32_bf16(a3, bfr[n][1], acc[m1][n], 0, 0, 0);
            }
            __builtin_amdgcn_s_setprio(0);
            __builtin_amdgcn_sched_barrier(0);
            if (p == 3) asm volatile("s_waitcnt vmcnt(0)" ::: "memory");  // next tile landed
            __builtin_amdgcn_s_barrier();
            __builtin_amdgcn_sched_barrier(0);
        }
    }

    const float* scrow = scale + (bm >> 1)*4096;   // 256-row tile stays in one batch
    #pragma unroll
    for (int n = 0; n < 4; ++n) {
        int gcol = bn*256 + wn*64 + n*16 + l16;
        float bc = bias[gcol];
        float sv = scrow[gcol];
        #pragma unroll
        for (int m = 0; m < 8; ++m) {
            int growb = bm*256 + wm*128 + m*16 + quad*4;
            #pragma unroll
            for (int r = 0; r < 4; ++r)
                out[(size_t)(growb + r)*4096 + gcol] = (acc[m][n][r] + bc) * sv;
        }
    }
}

extern "C" void kernel_launch(void* const* d_in, const int* in_sizes, int n_in,
                              void* d_out, int out_size, void* d_ws, size_t ws_size,
                              hipStream_t stream)
{
    const float* x     = (const float*)d_in[0];
    const float* Wsh   = (const float*)d_in[1];
    const float* bias  = (const float*)d_in[2];
    const float* left  = (const float*)d_in[3];
    const float* right = (const float*)d_in[4];
    const float* sbasis= (const float*)d_in[5];
    const float* w1    = (const float*)d_in[6];
    const float* b1    = (const float*)d_in[7];
    const float* rcw   = (const float*)d_in[8];
    const float* rcb   = (const float*)d_in[9];
    const float* rgw   = (const float*)d_in[10];
    const float* rgb   = (const float*)d_in[11];
    const float* scw   = (const float*)d_in[12];
    const float* scb   = (const float*)d_in[13];
    const float* sgw   = (const float*)d_in[14];
    const float* sgb   = (const float*)d_in[15];
    float* out = (float*)d_out;
    (void)in_sizes; (void)n_in; (void)out_size; (void)ws_size;

    char* wsp = (char*)d_ws;
    size_t off = 0;
    auto take = [&](size_t bytes) -> char* {
        char* p = wsp + off;
        off = (off + bytes + 255) & ~(size_t)255;
        return p;
    };
    u16*   xb   = (u16*)  take((size_t)ROWS*INF*2);     // 32 MB
    u16*   Wb   = (u16*)  take((size_t)OUTF*INF*2);     // 8 MB
    u16*   Utb  = (u16*)  take((size_t)128*1024*2);
    u16*   Yb   = (u16*)  take((size_t)ROWS*128*2);     // 4 MB
    u16*   Qb   = (u16*)  take((size_t)ROWS*128*2);     // 4 MB
    u16*   Vb   = (u16*)  take((size_t)OUTF*128*2);     // 1 MB
    u16*   Ptb  = (u16*)  take((size_t)32*128*128*2);   // 1 MB
    float* Uf   = (float*)take((size_t)1024*128*4);
    float* Gf   = (float*)take((size_t)128*128*4);
    float* ps   = (float*)take((size_t)32*8*1024*4);
    float* pq   = (float*)take((size_t)32*8*1024*4);
    float* rc   = (float*)take(32*8*4);
    float* sc   = (float*)take(32*8*4);
    float* rg   = (float*)take(32*4);
    float* sg   = (float*)take(32*4);
    float* nrm  = (float*)take(8*4);
    float* scl  = (float*)take((size_t)32*4096*4);

    k_cvt   <<<dim3(4096),   dim3(256), 0, stream>>>(Wsh, Wb, OUTF*INF/4);
    k_stats <<<dim3(8,32),   dim3(256), 0, stream>>>(x, xb, ps, pq);
    k_buildU<<<dim3(512),    dim3(256), 0, stream>>>(left, right, Uf, Utb);
    k_gram  <<<dim3(64),     dim3(256), 0, stream>>>(Uf, Gf);
    k_norms <<<dim3(8),      dim3(64),  0, stream>>>(Gf, nrm);
    k_ctrl  <<<dim3(32),     dim3(256), 0, stream>>>(x, ps, pq, w1, b1, rcw, rcb,
                                                     rgw, rgb, scw, scb, sgw, sgb,
                                                     rc, rg, sc, sg);
    k_solve <<<dim3(32),     dim3(1024), 0, stream>>>(Gf, rc, nrm, rg, Ptb);
    k_scale <<<dim3(512),    dim3(256), 0, stream>>>(sc, sbasis, sg, scl);
    // Y = x U            (16384 x 128, K=1024)
    k_gemm_bt<<<dim3(1,128,1), dim3(256), 0, stream>>>(xb, Utb, Yb, ROWS, 128, 1024, 0L, 0L, 0L);
    // Q = Y P  per batch (512 x 128, K=128)
    k_gemm_bt<<<dim3(1,4,32),  dim3(256), 0, stream>>>(Yb, Ptb, Qb, 512, 128, 128,
                                                       (long)512*128, (long)128*128, (long)512*128);
    // V = Wsh U          (4096 x 128, K=1024)
    k_gemm_bt<<<dim3(1,32,1),  dim3(256), 0, stream>>>(Wb, Utb, Vb, OUTF, 128, 1024, 0L, 0L, 0L);
    // out = (x W^T + Q V^T + bias) * scale
    k_main  <<<dim3(16,64), dim3(512), 0, stream>>>(xb, Wb, Qb, Vb, bias, scl, out);
}

// Round 12
// 775.629 us; speedup vs baseline: 1.0244x; 1.0244x over previous
//
#include <hip/hip_runtime.h>
#include <hip/hip_bf16.h>

typedef unsigned short u16;
typedef short short8 __attribute__((ext_vector_type(8)));
typedef float f32x4 __attribute__((ext_vector_type(4)));

#define B_    32
#define N_    512
#define INF   1024
#define OUTF  4096
#define ROWS  16384     // B_*N_
#define HID_  128
#define CTRL  3072

__device__ __forceinline__ u16 f2bf(float f) {
    union { float fv; unsigned int u; } v; v.fv = f;
    unsigned int x = v.u;
    unsigned int r = (x + 0x7fffu + ((x >> 16) & 1u)) >> 16;
    return (u16)r;
}

// async global->LDS, 16B per lane. lds ptr must be the WAVE-UNIFORM base;
// lane l deposits at base + l*16.
__device__ __forceinline__ void gll16(const void* g, const void* l) {
    __builtin_amdgcn_global_load_lds(
        (__attribute__((address_space(1))) void*)(unsigned long long)g,
        (__attribute__((address_space(3))) void*)(unsigned int)(unsigned long long)l,
        16, 0, 0);
}

// by-VALUE 16-way select (cndmask chain; no address taken -> no scratch demotion)
__device__ __forceinline__ float sel16(float4 a, float4 b, float4 c4, float4 d, int m) {
    float v = a.x;
    v = (m == 1) ? a.y : v;  v = (m == 2) ? a.z : v;  v = (m == 3) ? a.w : v;
    v = (m == 4) ? b.x : v;  v = (m == 5) ? b.y : v;  v = (m == 6) ? b.z : v;  v = (m == 7) ? b.w : v;
    v = (m == 8) ? c4.x : v; v = (m == 9) ? c4.y : v; v = (m == 10) ? c4.z : v; v = (m == 11) ? c4.w : v;
    v = (m == 12) ? d.x : v; v = (m == 13) ? d.y : v; v = (m == 14) ? d.z : v; v = (m == 15) ? d.w : v;
    return v;
}

// ------- stats (partial sums) + x->bf16 convert + W->bf16 convert (fused) --
// blocks 0..255: stats on x (b=blk>>3, bn=blk&7); blocks 256..4351: W cvt.
__global__ __launch_bounds__(256) void k_stats(const float* __restrict__ x,
        const float* __restrict__ W, u16* __restrict__ xb, u16* __restrict__ Wb,
        float* __restrict__ ps, float* __restrict__ pq) {
    int blk = blockIdx.x, t = threadIdx.x;
    if (blk >= 256) {                       // fused k_cvt: W -> Wb (bf16)
        int i = (blk - 256)*256 + t;        // 4096*256 = OUTF*INF/4 exactly
        float4 v = ((const float4*)W)[i];
        ushort4 o; o.x=f2bf(v.x); o.y=f2bf(v.y); o.z=f2bf(v.z); o.w=f2bf(v.w);
        ((ushort4*)Wb)[i] = o;
        return;
    }
    int b = blk >> 3, bn = blk & 7;
    const float4* xp = (const float4*)(x + (size_t)b*(N_*INF) + (size_t)bn*64*INF);
    size_t obase = ((size_t)b*(N_*INF) + (size_t)bn*64*INF) >> 2;
    float sx=0, sy=0, sz=0, sw=0, qx=0, qy=0, qz=0, qw=0;
    for (int n = 0; n < 64; ++n) {
        float4 v = xp[n*256 + t];
        sx += v.x; sy += v.y; sz += v.z; sw += v.w;
        qx += v.x*v.x; qy += v.y*v.y; qz += v.z*v.z; qw += v.w*v.w;
        ushort4 o; o.x = f2bf(v.x); o.y = f2bf(v.y); o.z = f2bf(v.z); o.w = f2bf(v.w);
        ((ushort4*)xb)[obase + n*256 + t] = o;
    }
    int base = (b*8 + bn)*256 + t;
    float4 s4; s4.x=sx; s4.y=sy; s4.z=sz; s4.w=sw;
    float4 q4; q4.x=qx; q4.y=qy; q4.z=qz; q4.w=qw;
    ((float4*)ps)[base] = s4;
    ((float4*)pq)[base] = q4;
}

// ---------------- control MLP: coalesced wave-per-row GEMV -----------------
__global__ __launch_bounds__(256) void k_ctrl(const float* __restrict__ x,
    const float* __restrict__ ps, const float* __restrict__ pq,
    const float* __restrict__ w1, const float* __restrict__ b1,
    const float* __restrict__ rcw, const float* __restrict__ rcb,
    const float* __restrict__ rgw, const float* __restrict__ rgb,
    const float* __restrict__ scw, const float* __restrict__ scb,
    const float* __restrict__ sgw, const float* __restrict__ sgb,
    float* __restrict__ rc, float* __restrict__ rg,
    float* __restrict__ sc, float* __restrict__ sg)
{
    __shared__ float zs[CTRL];
    __shared__ float hs[HID_];
    int b = blockIdx.x, t = threadIdx.x;
    for (int d = t; d < 1024; d += 256) {
        float ssum = 0.f, qsum = 0.f;
        for (int j = 0; j < 8; ++j) {
            ssum += ps[(b*8 + j)*1024 + d];
            qsum += pq[(b*8 + j)*1024 + d];
        }
        float mean = ssum * (1.0f/512.0f);
        float var  = qsum * (1.0f/512.0f) - mean*mean;
        zs[d]        = x[(size_t)b*(N_*INF) + d];
        zs[1024 + d] = mean;
        zs[2048 + d] = var;
    }
    __syncthreads();
    int w = t >> 6, l = t & 63;
    const float4* zp = (const float4*)zs;
    for (int i = w; i < HID_; i += 4) {
        const float4* wr = (const float4*)(w1 + (size_t)i*CTRL);
        float acc = 0.f;
        #pragma unroll
        for (int c = 0; c < 12; ++c) {
            float4 a4 = wr[l + 64*c];
            float4 z4 = zp[l + 64*c];
            acc += a4.x*z4.x + a4.y*z4.y + a4.z*z4.z + a4.w*z4.w;
        }
        #pragma unroll
        for (int o2 = 32; o2 > 0; o2 >>= 1) acc += __shfl_down(acc, o2, 64);
        if (l == 0) {
            float u = acc + b1[i];
            hs[i] = 0.5f*u*(1.0f + tanhf(0.7978845608028654f*(u + 0.044715f*u*u*u)));
        }
    }
    __syncthreads();
    if (t < 8) {
        float a = rcb[t]; const float* wv = rcw + t*HID_;
        for (int i = 0; i < HID_; ++i) a += hs[i]*wv[i];
        rc[b*8 + t] = a;
    } else if (t < 16) {
        int j = t - 8;
        float a = scb[j]; const float* wv = scw + j*HID_;
        for (int i = 0; i < HID_; ++i) a += hs[i]*wv[i];
        sc[b*8 + j] = a;
    } else if (t == 16) {
        float a = rgb[0] - 4.0f;
        for (int i = 0; i < HID_; ++i) a += hs[i]*rgw[i];
        rg[b] = 1.0f/(1.0f + expf(-a));
    } else if (t == 17) {
        float a = sgb[0] - 2.5f;
        for (int i = 0; i < HID_; ++i) a += hs[i]*sgw[i];
        sg[b] = 1.0f/(1.0f + expf(-a));
    }
}

// ---------------- build U (1024x128 f32) and U^T (bf16, 128x1024) ----------
__global__ __launch_bounds__(256) void k_buildU(const float* __restrict__ L,
        const float* __restrict__ R, float* __restrict__ U, u16* __restrict__ Utb) {
    int idx = blockIdx.x*256 + threadIdx.x;
    int d = idx >> 7, col = idx & 127;
    int k = col >> 4, rr = col & 15;
    float v = (rr < 8) ? L[((size_t)k<<13) + (d<<3) + rr]
                       : R[((size_t)k<<13) + (d<<3) + (rr-8)];
    U[idx] = v;
    Utb[col*1024 + d] = f2bf(v);
}

// ---------------- G = U^T U (128x128) --------------------------------------
__global__ __launch_bounds__(256) void k_gram(const float* __restrict__ U,
        float* __restrict__ G) {
    int e = blockIdx.x*256 + threadIdx.x;
    int i = e >> 7, j = e & 127;
    float a = 0.f;
    for (int d = 0; d < 1024; ++d) a += U[d*128 + i]*U[d*128 + j];
    G[e] = a;
}

// -------- per-batch 128x128 inversion + fused norms (prologue) + -----------
// -------- fused output-scale (epilogue). Register-resident GJ.   -----------
__global__ __launch_bounds__(1024, 4) void k_solve(const float* __restrict__ G,
    const float* __restrict__ rc, const float* __restrict__ rg,
    u16* __restrict__ Ptb, const float* __restrict__ sc,
    const float* __restrict__ sgv, const float* __restrict__ sbasis,
    float* __restrict__ scl)
{
    __shared__ float smem[16384];          // 64KB; first 512 floats = pivot bufs
    __shared__ float nrm_s[8];
    float* prow = smem;                    // [2][128]
    float* pcol = smem + 256;              // [2][128]
    int b = blockIdx.x, t = threadIdx.x;
    // ---- fused k_norms: waves 0-7 each compute one basis norm from G ----
    {
        int wv = t >> 6, ln = t & 63;
        if (wv < 8) {
            int i = ln >> 3, j = ln & 7;
            float A  = G[(16*wv + i)*128     + 16*wv + j];
            float C  = G[(16*wv + 8 + i)*128 + 16*wv + 8 + j];
            float D  = G[(16*wv + 8 + i)*128 + 16*wv + j];
            float Dj = G[(16*wv + 8 + j)*128 + 16*wv + i];
            float term = A*C - D*Dj;
            #pragma unroll
            for (int o2 = 32; o2 > 0; o2 >>= 1) term += __shfl_down(term, o2, 64);
            if (ln == 0) nrm_s[wv] = fmaxf(sqrtf(fmaxf(2.0f*term, 0.0f)), 1e-6f);
        }
    }
    __syncthreads();
    int r = t & 127, s = t >> 7;           // s is wave-uniform
    int kr = r >> 4, rr = r & 15;
    float a_r = rc[b*8 + kr] / nrm_s[kr];
    int partner = (rr < 8) ? (kr*16 + 8 + rr) : (kr*16 + rr - 8);
    float sg0 = (rr < 8) ? -0.5f*a_r : 0.5f*a_r;
    float4 o0, o1, o2, o3;
    {
        const float4* Gp = (const float4*)(G + (size_t)partner*128 + 16*s);
        float4 g0 = Gp[0], g1 = Gp[1], g2 = Gp[2], g3 = Gp[3];
        int base = 16*s;
        o0.x = sg0*g0.x + ((r == base+0 ) ? 1.f : 0.f);
        o0.y = sg0*g0.y + ((r == base+1 ) ? 1.f : 0.f);
        o0.z = sg0*g0.z + ((r == base+2 ) ? 1.f : 0.f);
        o0.w = sg0*g0.w + ((r == base+3 ) ? 1.f : 0.f);
        o1.x = sg0*g1.x + ((r == base+4 ) ? 1.f : 0.f);
        o1.y = sg0*g1.y + ((r == base+5 ) ? 1.f : 0.f);
        o1.z = sg0*g1.z + ((r == base+6 ) ? 1.f : 0.f);
        o1.w = sg0*g1.w + ((r == base+7 ) ? 1.f : 0.f);
        o2.x = sg0*g2.x + ((r == base+8 ) ? 1.f : 0.f);
        o2.y = sg0*g2.y + ((r == base+9 ) ? 1.f : 0.f);
        o2.z = sg0*g2.z + ((r == base+10) ? 1.f : 0.f);
        o2.w = sg0*g2.w + ((r == base+11) ? 1.f : 0.f);
        o3.x = sg0*g3.x + ((r == base+12) ? 1.f : 0.f);
        o3.y = sg0*g3.y + ((r == base+13) ? 1.f : 0.f);
        o3.z = sg0*g3.z + ((r == base+14) ? 1.f : 0.f);
        o3.w = sg0*g3.w + ((r == base+15) ? 1.f : 0.f);
    }
    if (r == 0) {
        float4 v0 = o0, v1 = o1, v2 = o2, v3 = o3;
        if (s == 0) v0.x += 1.0f;
        *(float4*)(prow + 16*s +  0) = v0;
        *(float4*)(prow + 16*s +  4) = v1;
        *(float4*)(prow + 16*s +  8) = v2;
        *(float4*)(prow + 16*s + 12) = v3;
    }
    if (s == 0) pcol[r] = o0.x;
    __syncthreads();
    for (int c = 0; c < 128; ++c) {
        int buf = c & 1, nb = buf ^ 1;
        float fr = pcol[buf*128 + r];
        const float4* prp = (const float4*)(prow + buf*128 + 16*s);
        float4 p0 = prp[0], p1 = prp[1], p2 = prp[2], p3 = prp[3];
        float pv = prow[buf*128 + c] - 1.0f;   // un-marked pivot value
        float invp = 1.0f / pv;
        if (r == c) {
            int base = 16*s;
            o0.x = (base+0  == c) ? invp : o0.x*invp;
            o0.y = (base+1  == c) ? invp : o0.y*invp;
            o0.z = (base+2  == c) ? invp : o0.z*invp;
            o0.w = (base+3  == c) ? invp : o0.w*invp;
            o1.x = (base+4  == c) ? invp : o1.x*invp;
            o1.y = (base+5  == c) ? invp : o1.y*invp;
            o1.z = (base+6  == c) ? invp : o1.z*invp;
            o1.w = (base+7  == c) ? invp : o1.w*invp;
            o2.x = (base+8  == c) ? invp : o2.x*invp;
            o2.y = (base+9  == c) ? invp : o2.y*invp;
            o2.z = (base+10 == c) ? invp : o2.z*invp;
            o2.w = (base+11 == c) ? invp : o2.w*invp;
            o3.x = (base+12 == c) ? invp : o3.x*invp;
            o3.y = (base+13 == c) ? invp : o3.y*invp;
            o3.z = (base+14 == c) ? invp : o3.z*invp;
            o3.w = (base+15 == c) ? invp : o3.w*invp;
        } else {
            float fi = fr * invp;
            o0.x -= fi*p0.x; o0.y -= fi*p0.y; o0.z -= fi*p0.z; o0.w -= fi*p0.w;
            o1.x -= fi*p1.x; o1.y -= fi*p1.y; o1.z -= fi*p1.z; o1.w -= fi*p1.w;
            o2.x -= fi*p2.x; o2.y -= fi*p2.y; o2.z -= fi*p2.z; o2.w -= fi*p2.w;
            o3.x -= fi*p3.x; o3.y -= fi*p3.y; o3.z -= fi*p3.z; o3.w -= fi*p3.w;
        }
        int cn = c + 1;
        if (cn < 128) {
            if (r == cn) {
                float4 v0 = o0, v1 = o1, v2 = o2, v3 = o3;
                int base = 16*s;
                v0.x += (base+0  == cn) ? 1.f : 0.f;
                v0.y += (base+1  == cn) ? 1.f : 0.f;
                v0.z += (base+2  == cn) ? 1.f : 0.f;
                v0.w += (base+3  == cn) ? 1.f : 0.f;
                v1.x += (base+4  == cn) ? 1.f : 0.f;
                v1.y += (base+5  == cn) ? 1.f : 0.f;
                v1.z += (base+6  == cn) ? 1.f : 0.f;
                v1.w += (base+7  == cn) ? 1.f : 0.f;
                v2.x += (base+8  == cn) ? 1.f : 0.f;
                v2.y += (base+9  == cn) ? 1.f : 0.f;
                v2.z += (base+10 == cn) ? 1.f : 0.f;
                v2.w += (base+11 == cn) ? 1.f : 0.f;
                v3.x += (base+12 == cn) ? 1.f : 0.f;
                v3.y += (base+13 == cn) ? 1.f : 0.f;
                v3.z += (base+14 == cn) ? 1.f : 0.f;
                v3.w += (base+15 == cn) ? 1.f : 0.f;
                *(float4*)(prow + nb*128 + 16*s +  0) = v0;
                *(float4*)(prow + nb*128 + 16*s +  4) = v1;
                *(float4*)(prow + nb*128 + 16*s +  8) = v2;
                *(float4*)(prow + nb*128 + 16*s + 12) = v3;
            }
            if (s == (cn >> 4)) pcol[nb*128 + r] = sel16(o0, o1, o2, o3, cn & 15);
        }
        __syncthreads();
    }
    float as_ = rc[b*8 + s] / nrm_s[s];
    float gg = rg[b];
    float na = -gg * as_, pa = gg * as_;
    smem[(16*s +  0)*128 + r] = na*o2.x;
    smem[(16*s +  1)*128 + r] = na*o2.y;
    smem[(16*s +  2)*128 + r] = na*o2.z;
    smem[(16*s +  3)*128 + r] = na*o2.w;
    smem[(16*s +  4)*128 + r] = na*o3.x;
    smem[(16*s +  5)*128 + r] = na*o3.y;
    smem[(16*s +  6)*128 + r] = na*o3.z;
    smem[(16*s +  7)*128 + r] = na*o3.w;
    smem[(16*s +  8)*128 + r] = pa*o0.x;
    smem[(16*s +  9)*128 + r] = pa*o0.y;
    smem[(16*s + 10)*128 + r] = pa*o0.z;
    smem[(16*s + 11)*128 + r] = pa*o0.w;
    smem[(16*s + 12)*128 + r] = pa*o1.x;
    smem[(16*s + 13)*128 + r] = pa*o1.y;
    smem[(16*s + 14)*128 + r] = pa*o1.z;
    smem[(16*s + 15)*128 + r] = pa*o1.w;
    __syncthreads();
    int r2 = t >> 3, s2 = t & 7;
    const float4* rp = (const float4*)(smem + r2*128 + 16*s2);
    float4 v0 = rp[0], v1 = rp[1], v2 = rp[2], v3 = rp[3];
    uint4 w0, w1;
    w0.x = f2bf(v0.x) | ((unsigned)f2bf(v0.y) << 16);
    w0.y = f2bf(v0.z) | ((unsigned)f2bf(v0.w) << 16);
    w0.z = f2bf(v1.x) | ((unsigned)f2bf(v1.y) << 16);
    w0.w = f2bf(v1.z) | ((unsigned)f2bf(v1.w) << 16);
    w1.x = f2bf(v2.x) | ((unsigned)f2bf(v2.y) << 16);
    w1.y = f2bf(v2.z) | ((unsigned)f2bf(v2.w) << 16);
    w1.z = f2bf(v3.x) | ((unsigned)f2bf(v3.y) << 16);
    w1.w = f2bf(v3.z) | ((unsigned)f2bf(v3.w) << 16);
    uint4* dst = (uint4*)(Ptb + ((size_t)(b*128 + r2))*128 + 16*s2);
    dst[0] = w0; dst[1] = w1;
    // ---- fused k_scale for batch b: scl = 1 + sg*tanh(sc @ sbasis) ----
    float sgb_ = sgv[b];
    for (int o = t; o < 4096; o += 1024) {
        float a2 = 0.f;
        #pragma unroll
        for (int k2 = 0; k2 < 8; ++k2) a2 += sc[b*8 + k2]*sbasis[(k2 << 12) + o];
        scl[b*4096 + o] = 1.0f + sgb_*tanhf(a2);
    }
}

// ---------------- generic bf16 MFMA GEMM: C[m,n] = sum_k A[m,k]*Bt[n,k] ----
__global__ __launch_bounds__(256) void k_gemm_bt(const u16* __restrict__ A,
    const u16* __restrict__ Bt, u16* __restrict__ C,
    int M, int N, int K, long sA_, long sB_, long sC_)
{
    A  += (size_t)blockIdx.z * sA_;
    Bt += (size_t)blockIdx.z * sB_;
    C  += (size_t)blockIdx.z * sC_;
    int bm = blockIdx.y, bn = blockIdx.x;
    __shared__ __align__(16) u16 sA[128*64];
    __shared__ __align__(16) u16 sB[128*64];
    int tid = threadIdx.x;
    int wave = tid >> 6, lane = tid & 63;
    int wbase = tid & ~63;
    int wm = wave >> 1, wn = wave & 1;
    int quad = lane >> 4, l16 = lane & 15;
    f32x4 acc[4][4];
    #pragma unroll
    for (int i = 0; i < 4; ++i)
        #pragma unroll
        for (int j = 0; j < 4; ++j) { f32x4 z4 = {0.f,0.f,0.f,0.f}; acc[i][j] = z4; }
    int nk = K >> 6;
    for (int kt = 0; kt < nk; ++kt) {
        __syncthreads();
        #pragma unroll
        for (int q2 = 0; q2 < 4; ++q2) {
            int c = q2*256 + tid, row = c >> 3, kc = c & 7;
            gll16(A  + (size_t)(bm*128 + row)*K + kt*64 + kc*8, sA + (size_t)(q2*256 + wbase)*8);
            gll16(Bt + (size_t)(bn*128 + row)*K + kt*64 + kc*8, sB + (size_t)(q2*256 + wbase)*8);
        }
        __syncthreads();
        #pragma unroll
        for (int ks = 0; ks < 2; ++ks) {
            short8 af[4], bfv[4];
            #pragma unroll
            for (int i = 0; i < 4; ++i)
                af[i] = *(const short8*)(sA + (wm*64 + i*16 + l16)*64 + ks*32 + quad*8);
            #pragma unroll
            for (int j = 0; j < 4; ++j)
                bfv[j] = *(const short8*)(sB + (wn*64 + j*16 + l16)*64 + ks*32 + quad*8);
            #pragma unroll
            for (int i = 0; i < 4; ++i)
                #pragma unroll
                for (int j = 0; j < 4; ++j)
                    acc[i][j] = __builtin_amdgcn_mfma_f32_16x16x32_bf16(af[i], bfv[j], acc[i][j], 0, 0, 0);
        }
    }
    #pragma unroll
    for (int i = 0; i < 4; ++i)
        #pragma unroll
        for (int j = 0; j < 4; ++j) {
            int gcol = bn*128 + wn*64 + j*16 + l16;
            #pragma unroll
            for (int r = 0; r < 4; ++r) {
                int grow = bm*128 + wm*64 + i*16 + quad*4 + r;
                C[(size_t)grow*N + gcol] = f2bf(acc[i][j][r]);
            }
        }
}

// ---------------- main fused GEMM, 256x256 tile / 8 waves / BK=64 ----------
// R7 VERIFIED VERSION (177.5us, MfmaUtil 37%, bank-conflict 0, 871 TF).
// Stage-early/wait-late 2-buffer schedule + st-swizzle + XCD chunking.
// R9's 4-phase split regressed (-8%: prefetch depth 1 + vmcnt(0) exposed HBM
// latency) -> reverted to this schedule.
__global__ __launch_bounds__(512, 2) void k_main(const u16* __restrict__ xb,
    const u16* __restrict__ Wb, const u16* __restrict__ Qb,
    const u16* __restrict__ Vb, const float* __restrict__ bias,
    const float* __restrict__ scale, float* __restrict__ out)
{
    __shared__ __align__(16) u16 lds[65536];       // 128 KB
    int flat = blockIdx.y * 16 + blockIdx.x;       // 0..1023
    int wg   = (flat & 7) * 128 + (flat >> 3);     // bijective XCD chunking
    int bm = wg >> 4, bn = wg & 15;                // 64 x 16
    int tid = threadIdx.x;
    int wave = tid >> 6, lane = tid & 63;
    int wm = wave >> 2, wn = wave & 3;             // 2 x 4 wave grid
    int quad = lane >> 4, l16 = lane & 15;

    int srow = wave*16 + (lane >> 3);                       // +8 for i=1
    int scol = (((lane & 7) ^ ((lane >> 3) & 7)) << 3);     // element col (x8)
    int arow0 = bm*256 + srow;
    int brow0 = bn*256 + srow;

    int cswz0 = (quad*16)      ^ ((l16 & 7) << 4);          // ks=0
    int cswz1 = (64 + quad*16) ^ ((l16 & 7) << 4);          // ks=1
    int abase = wm*16384 + l16*128;                         // A seg = wm
    int bbase = 32768 + (wn >> 1)*16384 + (wn & 1)*8192 + l16*128;

    auto stageg = [&](int kt, int bf) {
        u16* lb = lds + bf*32768;
        const u16 *As, *Bs; int str, ko;
        if (kt < 16) { As = xb; Bs = Wb; str = 1024; ko = kt*64 + scol; }
        else         { As = Qb; Bs = Vb; str = 128;  ko = (kt-16)*64 + scol; }
        #pragma unroll
        for (int i = 0; i < 2; ++i) {
            int r = i*8;
            gll16(As + (size_t)(arow0 + r)*str + ko,       lb +         wave*1024 + i*512);
            gll16(As + (size_t)(arow0 + 128 + r)*str + ko, lb +  8192 + wave*1024 + i*512);
            gll16(Bs + (size_t)(brow0 + r)*str + ko,       lb + 16384 + wave*1024 + i*512);
            gll16(Bs + (size_t)(brow0 + 128 + r)*str + ko, lb + 24576 + wave*1024 + i*512);
        }
    };

    f32x4 acc[8][4];
    #pragma unroll
    for (int m = 0; m < 8; ++m)
        #pragma unroll
        for (int n = 0; n < 4; ++n) { f32x4 z4 = {0.f,0.f,0.f,0.f}; acc[m][n] = z4; }

    // prologue: tiles 0 (buf0) and 1 (buf1)
    stageg(0, 0);
    stageg(1, 1);
    asm volatile("s_waitcnt vmcnt(8)" ::: "memory");   // tile0 landed; tile1 in flight
    __builtin_amdgcn_s_barrier();
    __builtin_amdgcn_sched_barrier(0);

    for (int it = 0; it < 9; ++it) {
        #pragma unroll
        for (int hf = 0; hf < 2; ++hf) {
            const char* lb = (const char*)lds + hf*65536;
            short8 bfr[4][2];
            #pragma unroll
            for (int n = 0; n < 4; ++n) {
                bfr[n][0] = *(const short8*)(lb + bbase + cswz0 + n*2048);
                bfr[n][1] = *(const short8*)(lb + bbase + cswz1 + n*2048);
            }
            // prefetch: stage the tile that replaces the buffer just freed
            if (hf == 0) { if (it >= 1) stageg(2*it + 1, 1); }
            else         { if (it <= 7) stageg(2*it + 2, 0); }
            __builtin_amdgcn_s_setprio(1);
            #pragma unroll
            for (int m = 0; m < 8; ++m) {
                short8 a0 = *(const short8*)(lb + abase + cswz0 + m*2048);
                short8 a1 = *(const short8*)(lb + abase + cswz1 + m*2048);
                #pragma unroll
                for (int n = 0; n < 4; ++n) {
                    acc[m][n] = __builtin_amdgcn_mfma_f32_16x16x32_bf16(a0, bfr[n][0], acc[m][n], 0, 0, 0);
                    acc[m][n] = __builtin_amdgcn_mfma_f32_16x16x32_bf16(a1, bfr[n][1], acc[m][n], 0, 0, 0);
                }
            }
            __builtin_amdgcn_s_setprio(0);
            __builtin_amdgcn_sched_barrier(0);
            asm volatile("s_waitcnt vmcnt(0)" ::: "memory");  // staged tile landed
            __builtin_amdgcn_s_barrier();
            __builtin_amdgcn_sched_barrier(0);
        }
    }

    const float* scrow = scale + (bm >> 1)*4096;   // 256-row tile stays in one batch
    #pragma unroll
    for (int n = 0; n < 4; ++n) {
        int gcol = bn*256 + wn*64 + n*16 + l16;
        float bc = bias[gcol];
        float sv = scrow[gcol];
        #pragma unroll
        for (int m = 0; m < 8; ++m) {
            int growb = bm*256 + wm*128 + m*16 + quad*4;
            #pragma unroll
            for (int r = 0; r < 4; ++r)
                out[(size_t)(growb + r)*4096 + gcol] = (acc[m][n][r] + bc) * sv;
        }
    }
}

extern "C" void kernel_launch(void* const* d_in, const int* in_sizes, int n_in,
                              void* d_out, int out_size, void* d_ws, size_t ws_size,
                              hipStream_t stream)
{
    const float* x     = (const float*)d_in[0];
    const float* Wsh   = (const float*)d_in[1];
    const float* bias  = (const float*)d_in[2];
    const float* left  = (const float*)d_in[3];
    const float* right = (const float*)d_in[4];
    const float* sbasis= (const float*)d_in[5];
    const float* w1    = (const float*)d_in[6];
    const float* b1    = (const float*)d_in[7];
    const float* rcw   = (const float*)d_in[8];
    const float* rcb   = (const float*)d_in[9];
    const float* rgw   = (const float*)d_in[10];
    const float* rgb   = (const float*)d_in[11];
    const float* scw   = (const float*)d_in[12];
    const float* scb   = (const float*)d_in[13];
    const float* sgw   = (const float*)d_in[14];
    const float* sgb   = (const float*)d_in[15];
    float* out = (float*)d_out;
    (void)in_sizes; (void)n_in; (void)out_size; (void)ws_size;

    char* wsp = (char*)d_ws;
    size_t off = 0;
    auto take = [&](size_t bytes) -> char* {
        char* p = wsp + off;
        off = (off + bytes + 255) & ~(size_t)255;
        return p;
    };
    u16*   xb   = (u16*)  take((size_t)ROWS*INF*2);     // 32 MB
    u16*   Wb   = (u16*)  take((size_t)OUTF*INF*2);     // 8 MB
    u16*   Utb  = (u16*)  take((size_t)128*1024*2);
    u16*   Yb   = (u16*)  take((size_t)ROWS*128*2);     // 4 MB
    u16*   Qb   = (u16*)  take((size_t)ROWS*128*2);     // 4 MB
    u16*   Vb   = (u16*)  take((size_t)OUTF*128*2);     // 1 MB
    u16*   Ptb  = (u16*)  take((size_t)32*128*128*2);   // 1 MB
    float* Uf   = (float*)take((size_t)1024*128*4);
    float* Gf   = (float*)take((size_t)128*128*4);
    float* ps   = (float*)take((size_t)32*8*1024*4);
    float* pq   = (float*)take((size_t)32*8*1024*4);
    float* rc   = (float*)take(32*8*4);
    float* sc   = (float*)take(32*8*4);
    float* rg   = (float*)take(32*4);
    float* sg   = (float*)take(32*4);
    float* scl  = (float*)take((size_t)32*4096*4);

    // fused: stats (blocks 0-255) + W->bf16 cvt (blocks 256-4351)
    k_stats <<<dim3(4352),   dim3(256), 0, stream>>>(x, Wsh, xb, Wb, ps, pq);
    k_buildU<<<dim3(512),    dim3(256), 0, stream>>>(left, right, Uf, Utb);
    k_gram  <<<dim3(64),     dim3(256), 0, stream>>>(Uf, Gf);
    k_ctrl  <<<dim3(32),     dim3(256), 0, stream>>>(x, ps, pq, w1, b1, rcw, rcb,
                                                     rgw, rgb, scw, scb, sgw, sgb,
                                                     rc, rg, sc, sg);
    // fused: norms (prologue) + GJ inversion + output-scale (epilogue)
    k_solve <<<dim3(32),     dim3(1024), 0, stream>>>(Gf, rc, rg, Ptb, sc, sg,
                                                      sbasis, scl);
    // Y = x U            (16384 x 128, K=1024)
    k_gemm_bt<<<dim3(1,128,1), dim3(256), 0, stream>>>(xb, Utb, Yb, ROWS, 128, 1024, 0L, 0L, 0L);
    // Q = Y P  per batch (512 x 128, K=128)
    k_gemm_bt<<<dim3(1,4,32),  dim3(256), 0, stream>>>(Yb, Ptb, Qb, 512, 128, 128,
                                                       (long)512*128, (long)128*128, (long)512*128);
    // V = Wsh U          (4096 x 128, K=1024)
    k_gemm_bt<<<dim3(1,32,1),  dim3(256), 0, stream>>>(Wb, Utb, Vb, OUTF, 128, 1024, 0L, 0L, 0L);
    // out = (x W^T + Q V^T + bias) * scale
    k_main  <<<dim3(16,64), dim3(512), 0, stream>>>(xb, Wb, Qb, Vb, bias, scl, out);
}